// Round 12
// baseline (132.348 us; speedup 1.0000x reference)
//
#include <hip/hip_runtime.h>
#include <hip/hip_bf16.h>

// Problem constants
#define NB 16384      // batch rows
#define DD 512        // IN+OUT
#define NCOLS 4096    // 4*OUT*NCELL
#define MAXCHUNK 272  // 8 XCD-aligned upper bound on 64-row chunks (261 max real)

typedef __attribute__((ext_vector_type(8))) short short8;
typedef __attribute__((ext_vector_type(4))) float f32x4;

__device__ __forceinline__ float sigmoidf_(float x) {
    return 1.f / (1.f + __expf(-x));
}
__device__ __forceinline__ float tanhf_(float x) {
    float e = __expf(-2.f * fabsf(x));      // in (0,1], no overflow
    float t = (1.f - e) / (1.f + e);
    return copysignf(t, x);
}

#define GLOAD_LDS16(g, l) __builtin_amdgcn_global_load_lds( \
    (__attribute__((address_space(1))) void*)(g), \
    (__attribute__((address_space(3))) void*)(l), 16, 0, 0)

// Shared bucket-chunk decode: bq -> (pair p, chunk, nvalid, rowbase, cells cA/cB)
__device__ __forceinline__ bool chunk_decode(const int* counts, int bq,
                                             int& p, int& nvalid, int& rowbase,
                                             int& cA, int& cB) {
    int c0_ = counts[0], c1_ = counts[1], c2_ = counts[2],
        c3_ = counts[3], c4_ = counts[4], c5_ = counts[5];
    int s1 = (c0_ + 63) >> 6;
    int s2 = s1 + ((c1_ + 63) >> 6);
    int s3 = s2 + ((c2_ + 63) >> 6);
    int s4 = s3 + ((c3_ + 63) >> 6);
    int s5 = s4 + ((c4_ + 63) >> 6);
    int total = s5 + ((c5_ + 63) >> 6);
    if (bq >= total) return false;
    int chunk, cnt;
    if      (bq < s1) { p = 0; chunk = bq;      cnt = c0_; cA = 0; cB = 1; }
    else if (bq < s2) { p = 1; chunk = bq - s1; cnt = c1_; cA = 0; cB = 2; }
    else if (bq < s3) { p = 2; chunk = bq - s2; cnt = c2_; cA = 0; cB = 3; }
    else if (bq < s4) { p = 3; chunk = bq - s3; cnt = c3_; cA = 1; cB = 2; }
    else if (bq < s5) { p = 4; chunk = bq - s4; cnt = c4_; cA = 1; cB = 3; }
    else              { p = 5; chunk = bq - s5; cnt = c5_; cA = 2; cB = 3; }
    nvalid = min(64, cnt - chunk * 64);
    rowbase = p * 16384 + chunk * 64;
    return true;
}

// ---------------- P1 (fused): ctrl gates | W_gates repack ----------
// blocks 0..4095: gates (wave-per-row; featsB no longer stored — k_perm builds
// the bucket-ordered bf16 copy directly from x,h).  blocks 4096..5119: repack.
__global__ void k_pre(const float* __restrict__ x, const float* __restrict__ h,
                      const float* __restrict__ Wc, const float* __restrict__ bc,
                      const float* __restrict__ Wg,
                      float* __restrict__ gates,
                      __hip_bfloat16* __restrict__ W3) {
    int bid = blockIdx.x;
    if (bid < 4096) {
        int wave = bid * 4 + (threadIdx.x >> 6);  // == row
        int lane = threadIdx.x & 63;
        int row = wave;
        int k0 = lane * 8;
        const float* src = (k0 < 256) ? (x + (size_t)row * 256 + k0)
                                      : (h + (size_t)row * 256 + k0 - 256);
        float4 f0 = ((const float4*)src)[0];
        float4 f1 = ((const float4*)src)[1];
        float fv[8] = {f0.x, f0.y, f0.z, f0.w, f1.x, f1.y, f1.z, f1.w};
        float acc[4] = {0.f, 0.f, 0.f, 0.f};
#pragma unroll
        for (int j = 0; j < 8; ++j) {
            float4 w = ((const float4*)Wc)[k0 + j];
            acc[0] += fv[j] * w.x; acc[1] += fv[j] * w.y;
            acc[2] += fv[j] * w.z; acc[3] += fv[j] * w.w;
        }
#pragma unroll
        for (int off = 32; off; off >>= 1) {
#pragma unroll
            for (int c = 0; c < 4; ++c) acc[c] += __shfl_xor(acc[c], off);
        }
        if (lane == 0) {
            float l[4];
#pragma unroll
            for (int c = 0; c < 4; ++c) l[c] = acc[c] + bc[c];
            int i1 = 0;
#pragma unroll
            for (int c = 1; c < 4; ++c) if (l[c] > l[i1]) i1 = c;  // ties -> lowest
            int i2 = -1;
#pragma unroll
            for (int c = 0; c < 4; ++c)
                if (c != i1 && (i2 < 0 || l[c] > l[i2])) i2 = c;
            float e = __expf(l[i2] - l[i1]);   // <= 1
            float p1 = 1.f / (1.f + e);
            float p2 = e / (1.f + e);
            float g[4] = {0.f, 0.f, 0.f, 0.f};
            g[i1] = p1; g[i2] = p2;
            float4 gv; gv.x = g[0]; gv.y = g[1]; gv.z = g[2]; gv.w = g[3];
            *(float4*)(gates + (size_t)row * 4) = gv;
        }
    } else {
        // W3 row index: cell*1024 + ob*128 + oh*64 + gate*16 + oi  (o=ob*32+oh*16+oi)
        int t = (bid - 4096) * 256 + threadIdx.x;
        int k0 = (t >> 12) * 8;
        int col = t & 4095;
        int cell = col >> 10, gate = (col >> 8) & 3, o = col & 255;
        int ob = o >> 5, oh = (o >> 4) & 1, oi = o & 15;
        int w3row = cell * 1024 + ob * 128 + oh * 64 + gate * 16 + oi;
        __hip_bfloat16 tmp[8];
#pragma unroll
        for (int j = 0; j < 8; ++j)
            tmp[j] = __float2bfloat16(Wg[(size_t)(k0 + j) * 4096 + col]);
        *reinterpret_cast<short8*>(W3 + (size_t)w3row * 512 + k0) =
            *reinterpret_cast<short8*>(tmp);
    }
}

// ---------------- P2: bucket rows by active cell-pair (wave-aggregated atomics) ----
__global__ void k_bucket(const float* __restrict__ gates, int* __restrict__ counts,
                         int* __restrict__ rowList) {
    int row = blockIdx.x * 256 + threadIdx.x;
    int lane = threadIdx.x & 63;
    float4 g = *(const float4*)(gates + (size_t)row * 4);
    int i1 = 0; float m1 = g.x;
    if (g.y > m1) { m1 = g.y; i1 = 1; }
    if (g.z > m1) { m1 = g.z; i1 = 2; }
    if (g.w > m1) { m1 = g.w; i1 = 3; }
    int i2 = -1; float m2 = -1.f;
    if (i1 != 0)             { m2 = g.x; i2 = 0; }
    if (i1 != 1 && g.y > m2) { m2 = g.y; i2 = 1; }
    if (i1 != 2 && g.z > m2) { m2 = g.z; i2 = 2; }
    if (i1 != 3 && g.w > m2) { m2 = g.w; i2 = 3; }
    int a = min(i1, i2), b = max(i1, i2);
    int pid = (a == 0) ? (b - 1) : (a == 1) ? (1 + b) : 5;
#pragma unroll
    for (int q = 0; q < 6; ++q) {
        unsigned long long m = __ballot(pid == q);   // uniform execution
        if (pid == q) {
            int leader = __ffsll((long long)m) - 1;
            int base = 0;
            if (lane == leader) base = atomicAdd(counts + q, __popcll(m));
            base = __shfl(base, leader);
            int prefix = __popcll(m & ((1ull << lane) - 1ull));
            rowList[q * 16384 + base + prefix] = row;
        }
    }
}

// ---------------- P3: bucket-ordered bf16 A-matrix (physical gather-permute) ----
// featsBP[bq*64 + r][k] = bf16(concat(x,h)[rowList[rowbase+r]][k]); padding rows
// duplicate slot 0 (results discarded via the out-write nvalid guard in k_main).
// Makes k_main's A-stage fully contiguous/coalesced — no per-row gather.
__launch_bounds__(256, 4)
__global__ void k_perm(const float* __restrict__ x, const float* __restrict__ h,
                       const int* __restrict__ counts, const int* __restrict__ rowList,
                       __hip_bfloat16* __restrict__ featsBP) {
    int bq = blockIdx.x;
    int p, nvalid, rowbase, cA, cB;
    if (!chunk_decode(counts, bq, p, nvalid, rowbase, cA, cB)) return;
    int tid = threadIdx.x;
#pragma unroll
    for (int i = 0; i < 16; ++i) {          // 64 rows x 64 16B-chunks = 4096 units
        int e = i * 256 + tid;
        int r = e >> 6, cc = e & 63;
        int row = rowList[rowbase + ((r < nvalid) ? r : 0)];
        int k0 = cc * 8;
        const float* src = (k0 < 256) ? (x + (size_t)row * 256 + k0)
                                      : (h + (size_t)row * 256 + (k0 - 256));
        float4 a = ((const float4*)src)[0];
        float4 b = ((const float4*)src)[1];
        __hip_bfloat16 tmp[8];
        tmp[0] = __float2bfloat16(a.x); tmp[1] = __float2bfloat16(a.y);
        tmp[2] = __float2bfloat16(a.z); tmp[3] = __float2bfloat16(a.w);
        tmp[4] = __float2bfloat16(b.x); tmp[5] = __float2bfloat16(b.y);
        tmp[6] = __float2bfloat16(b.z); tmp[7] = __float2bfloat16(b.w);
        *reinterpret_cast<short8*>(featsBP + ((size_t)bq * 64 + r) * 512 + k0) =
            *reinterpret_cast<short8*>(tmp);
    }
}

// ---------------- Main: pair-bucketed GEMM + LSTM epilogue --------------------
// R10-proven loop (BK=64, single 40960-B buffer, two __syncthreads per tile,
// 4 blocks/CU). R11 changes are ADDRESSING ONLY:
//  * XCD key swapped to ob (lin = bq*8 + ob -> XCD = ob): within an XCD, blocks
//    arrive in pair-major bq order, so the (pair, ob) W3 slice (256 KB) stays
//    L2-resident -> B staging waits on L2 (~200cy) instead of thrashed L3.
//  * A staged from featsBP (bucket-ordered): contiguous coalesced, no gather.
__launch_bounds__(256, 4)
__global__ void k_main(const __hip_bfloat16* __restrict__ featsBP,
                       const __hip_bfloat16* __restrict__ W3,
                       const float* __restrict__ cin,
                       const float* __restrict__ gates,
                       const float* __restrict__ bg,
                       const int* __restrict__ counts,
                       const int* __restrict__ rowList,
                       float* __restrict__ out) {
    __shared__ char smem[40960];          // As 8K | Bs 32K ; oAcc 16K aliases
    char* As = smem;
    char* Bs = smem + 8192;
    float* oAcc = (float*)smem;           // [2][64][32] f32 (epilogue)

    int tid = threadIdx.x;
    int wave = tid >> 6, lane = tid & 63;
    int wc = wave;                        // (ch, ohh) selector
    int hi = lane >> 4, lsw = lane & 7, l15 = lane & 15;

    int lin = blockIdx.x;                 // [0, 2176)
    int ob = lin & 7;                     // XCD = ob (B-slice L2-resident per XCD)
    int bq = lin >> 3;                    // pair-major chunk order within XCD

    int p, nvalid, rowbase, cA, cB;
    if (!chunk_decode(counts, bq, p, nvalid, rowbase, cA, cB)) return;

    // A staging: contiguous rows of featsBP; 128-B rows = 8 chunks; key = row&7
    int e0 = tid,        rA0 = e0 >> 3, gA0 = (e0 & 7) ^ (rA0 & 7);
    int e1 = 256 + tid,  rA1 = e1 >> 3, gA1 = (e1 & 7) ^ (rA1 & 7);
    const __hip_bfloat16* sA0 = featsBP + ((size_t)bq * 64 + rA0) * 512 + gA0 * 8;
    const __hip_bfloat16* sA1 = featsBP + ((size_t)bq * 64 + rA1) * 512 + gA1 * 8;
    int dA0 = e0 * 16, dA1 = e1 * 16;

    // B: dest chunk e = j*256 + tid -> dest row = j*32 + t8 == source row.
    int t8 = tid >> 3;
    int cswB = (tid & 7) ^ (t8 & 7);
    const __hip_bfloat16* sB_A = W3 + (size_t)(cA * 1024 + ob * 128 + t8) * 512 + cswB * 8;
    const __hip_bfloat16* sB_B = W3 + (size_t)(cB * 1024 + ob * 128 + t8) * 512 + cswB * 8;
    int dB = tid * 16;

    f32x4 acc[4][4];
#pragma unroll
    for (int m = 0; m < 4; ++m)
#pragma unroll
        for (int n = 0; n < 4; ++n)
            acc[m][n] = (f32x4){0.f, 0.f, 0.f, 0.f};

    for (int kt = 0; kt < 8; ++kt) {
        int ko = kt * 64;
        GLOAD_LDS16(sA0 + ko, As + dA0);
        GLOAD_LDS16(sA1 + ko, As + dA1);
#pragma unroll
        for (int j = 0; j < 4; ++j)   // cA half: rows j*32+t8 -> bytes j*4096+dB
            GLOAD_LDS16(sB_A + (size_t)j * 32 * 512 + ko, Bs + dB + j * 4096);
#pragma unroll
        for (int j = 0; j < 4; ++j)   // cB half: rows 128+j*32+t8
            GLOAD_LDS16(sB_B + (size_t)j * 32 * 512 + ko, Bs + 16384 + dB + j * 4096);
        __syncthreads();   // drains vmcnt + barrier
#pragma unroll
        for (int kk = 0; kk < 2; ++kk) {
            short8 fa[4], fb[4];
#pragma unroll
            for (int m = 0; m < 4; ++m) {
                int row = m * 16 + l15;
                int chunkc = (kk * 4 + hi) ^ lsw;
                fa[m] = *reinterpret_cast<const short8*>(As + row * 128 + chunkc * 16);
            }
#pragma unroll
            for (int n = 0; n < 4; ++n) {
                int c2 = wc * 64 + n * 16 + l15;   // = ch*128 + ohh*64 + gate*16 + oi
                int chunkc = (kk * 4 + hi) ^ lsw;
                fb[n] = *reinterpret_cast<const short8*>(Bs + c2 * 128 + chunkc * 16);
            }
#pragma unroll
            for (int m = 0; m < 4; ++m)
#pragma unroll
                for (int n = 0; n < 4; ++n)
                    acc[m][n] = __builtin_amdgcn_mfma_f32_16x16x32_bf16(
                        fa[m], fb[n], acc[m][n], 0, 0, 0);
        }
        __syncthreads();
    }

    // ---- epilogue: per-wave LSTM (all 4 gates in-register), 2-way pair reduce ----
    int ohh = wc & 1;
    int ch  = wc >> 1;
    int cell = ch ? cB : cA;
    int og = ob * 32 + ohh * 16 + l15;    // global o in [0,256)
    float bb0 = bg[cell * 1024 + 0 * 256 + og];
    float bb1 = bg[cell * 1024 + 1 * 256 + og];
    float bb2 = bg[cell * 1024 + 2 * 256 + og];
    float bb3 = bg[cell * 1024 + 3 * 256 + og];

#define LSTM_BODY(STORE_OP) \
    _Pragma("unroll") \
    for (int m = 0; m < 4; ++m) { \
        _Pragma("unroll") \
        for (int reg = 0; reg < 4; ++reg) { \
            int r = m * 16 + hi * 4 + reg; \
            int grow = rowList[rowbase + ((r < nvalid) ? r : 0)]; \
            float gw = gates[(size_t)grow * 4 + cell]; \
            float iv = sigmoidf_(acc[m][0][reg] + bb0); \
            float jv = acc[m][1][reg] + bb1; \
            float fv = sigmoidf_(acc[m][2][reg] + bb2); \
            float ov = sigmoidf_(acc[m][3][reg] + bb3); \
            float cv = cin[(size_t)grow * 256 + og]; \
            float ncl = fv * cv + iv * tanhf_(jv); \
            float nhl = ov * tanhf_(ncl); \
            oAcc[r * 32 + ohh * 16 + l15] STORE_OP gw * nhl; \
            oAcc[2048 + r * 32 + ohh * 16 + l15] STORE_OP gw * ncl; \
        } \
    }

    if (ch == 0) { LSTM_BODY(=) }     // cell-A waves cover all [2][64][32] slots
    __syncthreads();
    if (ch == 1) { LSTM_BODY(+=) }    // cell-B waves accumulate
    __syncthreads();
#undef LSTM_BODY

    {
        int r = tid >> 2, q = tid & 3;
        if (r < nvalid) {
            int grow = rowList[rowbase + r];
            size_t obase = (size_t)grow * 256 + ob * 32 + q * 8;
            *(float4*)&out[obase]     = *(float4*)&oAcc[r * 32 + q * 8];
            *(float4*)&out[obase + 4] = *(float4*)&oAcc[r * 32 + q * 8 + 4];
            *(float4*)&out[(size_t)NB * 256 + obase]     = *(float4*)&oAcc[2048 + r * 32 + q * 8];
            *(float4*)&out[(size_t)NB * 256 + obase + 4] = *(float4*)&oAcc[2048 + r * 32 + q * 8 + 4];
        }
    }
}

extern "C" void kernel_launch(void* const* d_in, const int* in_sizes, int n_in,
                              void* d_out, int out_size, void* d_ws, size_t ws_size,
                              hipStream_t stream) {
    const float* x  = (const float*)d_in[0];
    const float* c  = (const float*)d_in[1];
    const float* h  = (const float*)d_in[2];
    const float* Wg = (const float*)d_in[3];
    const float* bg = (const float*)d_in[4];
    const float* Wc = (const float*)d_in[5];
    const float* bc = (const float*)d_in[6];
    float* out = (float*)d_out;

    const size_t featsBP_bytes = (size_t)MAXCHUNK * 64 * DD * 2;  // 17.83 MB
    const size_t w3_bytes      = (size_t)NCOLS * DD * 2;          // 4.19 MB
    const size_t gates_bytes   = (size_t)NB * 4 * 4;              // 0.26 MB
    const size_t counts_bytes  = 256;
    const size_t rlist_bytes   = (size_t)6 * 16384 * 4;           // 0.39 MB
    if (ws_size < featsBP_bytes + w3_bytes + gates_bytes + counts_bytes + rlist_bytes)
        return;

    char* ws = (char*)d_ws;
    __hip_bfloat16* featsBP = (__hip_bfloat16*)ws;
    __hip_bfloat16* W3      = (__hip_bfloat16*)(ws + featsBP_bytes);
    float*          gatesW  = (float*)(ws + featsBP_bytes + w3_bytes);
    int*            counts  = (int*)(ws + featsBP_bytes + w3_bytes + gates_bytes);
    int*            rowLst  = (int*)(ws + featsBP_bytes + w3_bytes + gates_bytes + counts_bytes);

    hipMemsetAsync(counts, 0, 32, stream);
    k_pre<<<dim3(5120), dim3(256), 0, stream>>>(x, h, Wc, bc, Wg, gatesW, W3);
    k_bucket<<<dim3(64), dim3(256), 0, stream>>>(gatesW, counts, rowLst);
    k_perm<<<dim3(MAXCHUNK), dim3(256), 0, stream>>>(x, h, counts, rowLst, featsBP);
    // 2176 = 272 bq x 8 obs; lin = bq*8 + ob so XCD == ob; excess bq exit early
    k_main<<<dim3(MAXCHUNK * 8), dim3(256), 0, stream>>>(featsBP, W3, c, gatesW, bg,
                                                         counts, rowLst, out);
}

// Round 13
// 126.842 us; speedup vs baseline: 1.0434x; 1.0434x over previous
//
#include <hip/hip_runtime.h>
#include <hip/hip_bf16.h>

// Problem constants
#define NB 16384      // batch rows
#define DD 512        // IN+OUT
#define NCOLS 4096    // 4*OUT*NCELL

typedef __attribute__((ext_vector_type(8))) short short8;
typedef __attribute__((ext_vector_type(4))) float f32x4;

__device__ __forceinline__ float sigmoidf_(float x) {
    return 1.f / (1.f + __expf(-x));
}
__device__ __forceinline__ float tanhf_(float x) {
    float e = __expf(-2.f * fabsf(x));      // in (0,1], no overflow
    float t = (1.f - e) / (1.f + e);
    return copysignf(t, x);
}

// ---------------- P1 (fused): feats->bf16 + ctrl gates | W_gates repack ----------
__global__ void k_pre(const float* __restrict__ x, const float* __restrict__ h,
                      const float* __restrict__ Wc, const float* __restrict__ bc,
                      const float* __restrict__ Wg,
                      __hip_bfloat16* __restrict__ featsB, float* __restrict__ gates,
                      __hip_bfloat16* __restrict__ W3) {
    int bid = blockIdx.x;
    if (bid < 4096) {
        int wave = bid * 4 + (threadIdx.x >> 6);  // == row
        int lane = threadIdx.x & 63;
        int row = wave;
        int k0 = lane * 8;
        const float* src = (k0 < 256) ? (x + (size_t)row * 256 + k0)
                                      : (h + (size_t)row * 256 + k0 - 256);
        float4 f0 = ((const float4*)src)[0];
        float4 f1 = ((const float4*)src)[1];
        float fv[8] = {f0.x, f0.y, f0.z, f0.w, f1.x, f1.y, f1.z, f1.w};
        __hip_bfloat16 tmp[8];
#pragma unroll
        for (int j = 0; j < 8; ++j) tmp[j] = __float2bfloat16(fv[j]);
        *reinterpret_cast<short8*>(featsB + (size_t)row * 512 + k0) =
            *reinterpret_cast<short8*>(tmp);
        float acc[4] = {0.f, 0.f, 0.f, 0.f};
#pragma unroll
        for (int j = 0; j < 8; ++j) {
            float4 w = ((const float4*)Wc)[k0 + j];
            acc[0] += fv[j] * w.x; acc[1] += fv[j] * w.y;
            acc[2] += fv[j] * w.z; acc[3] += fv[j] * w.w;
        }
#pragma unroll
        for (int off = 32; off; off >>= 1) {
#pragma unroll
            for (int c = 0; c < 4; ++c) acc[c] += __shfl_xor(acc[c], off);
        }
        if (lane == 0) {
            float l[4];
#pragma unroll
            for (int c = 0; c < 4; ++c) l[c] = acc[c] + bc[c];
            int i1 = 0;
#pragma unroll
            for (int c = 1; c < 4; ++c) if (l[c] > l[i1]) i1 = c;  // ties -> lowest
            int i2 = -1;
#pragma unroll
            for (int c = 0; c < 4; ++c)
                if (c != i1 && (i2 < 0 || l[c] > l[i2])) i2 = c;
            float e = __expf(l[i2] - l[i1]);   // <= 1
            float p1 = 1.f / (1.f + e);
            float p2 = e / (1.f + e);
            float g[4] = {0.f, 0.f, 0.f, 0.f};
            g[i1] = p1; g[i2] = p2;
            float4 gv; gv.x = g[0]; gv.y = g[1]; gv.z = g[2]; gv.w = g[3];
            *(float4*)(gates + (size_t)row * 4) = gv;
        }
    } else {
        // W3 row index: cell*1024 + ob*128 + oh*64 + gate*16 + oi  (o=ob*32+oh*16+oi)
        int t = (bid - 4096) * 256 + threadIdx.x;
        int k0 = (t >> 12) * 8;
        int col = t & 4095;
        int cell = col >> 10, gate = (col >> 8) & 3, o = col & 255;
        int ob = o >> 5, oh = (o >> 4) & 1, oi = o & 15;
        int w3row = cell * 1024 + ob * 128 + oh * 64 + gate * 16 + oi;
        __hip_bfloat16 tmp[8];
#pragma unroll
        for (int j = 0; j < 8; ++j)
            tmp[j] = __float2bfloat16(Wg[(size_t)(k0 + j) * 4096 + col]);
        *reinterpret_cast<short8*>(W3 + (size_t)w3row * 512 + k0) =
            *reinterpret_cast<short8*>(tmp);
    }
}

// ---------------- P2: bucket rows by active cell-pair (wave-aggregated atomics) ----
__global__ void k_bucket(const float* __restrict__ gates, int* __restrict__ counts,
                         int* __restrict__ rowList) {
    int row = blockIdx.x * 256 + threadIdx.x;
    int lane = threadIdx.x & 63;
    float4 g = *(const float4*)(gates + (size_t)row * 4);
    int i1 = 0; float m1 = g.x;
    if (g.y > m1) { m1 = g.y; i1 = 1; }
    if (g.z > m1) { m1 = g.z; i1 = 2; }
    if (g.w > m1) { m1 = g.w; i1 = 3; }
    int i2 = -1; float m2 = -1.f;
    if (i1 != 0)             { m2 = g.x; i2 = 0; }
    if (i1 != 1 && g.y > m2) { m2 = g.y; i2 = 1; }
    if (i1 != 2 && g.z > m2) { m2 = g.z; i2 = 2; }
    if (i1 != 3 && g.w > m2) { m2 = g.w; i2 = 3; }
    int a = min(i1, i2), b = max(i1, i2);
    int pid = (a == 0) ? (b - 1) : (a == 1) ? (1 + b) : 5;
#pragma unroll
    for (int q = 0; q < 6; ++q) {
        unsigned long long m = __ballot(pid == q);   // uniform execution
        if (pid == q) {
            int leader = __ffsll((long long)m) - 1;
            int base = 0;
            if (lane == leader) base = atomicAdd(counts + q, __popcll(m));
            base = __shfl(base, leader);
            int prefix = __popcll(m & ((1ull << lane) - 1ull));
            rowList[q * 16384 + base + prefix] = row;
        }
    }
}

// ---------------- Main: pair-bucketed GEMM + LSTM, T14 reg-staged pipeline -------
// R10 partition/addresses verbatim (256 thr, 64 rows x 256 cols, BK=64, 40960-B
// single LDS buffer, proven swizzle). ONLY the staging changed: tile t+1 is
// loaded global->VGPR while tile t computes; the __syncthreads vmcnt(0) drain
// then lands AFTER the compute phase (latency covered), and ds_write moves the
// regs into LDS. Plain __syncthreads only — no manual vmcnt (R6 lesson).
// (256,3): VGPR cap ~170 for acc(64)+stage(40)+frags(32)+addr — no spill.
__launch_bounds__(256, 3)
__global__ void k_main(const __hip_bfloat16* __restrict__ featsB,
                       const __hip_bfloat16* __restrict__ W3,
                       const float* __restrict__ cin,
                       const float* __restrict__ gates,
                       const float* __restrict__ bg,
                       const int* __restrict__ counts,
                       const int* __restrict__ rowList,
                       float* __restrict__ out) {
    __shared__ char smem[40960];          // As 8K | Bs 32K ; oAcc 16K aliases
    char* As = smem;
    char* Bs = smem + 8192;
    float* oAcc = (float*)smem;           // [2][64][32] f32 (epilogue)

    int tid = threadIdx.x;
    int wave = tid >> 6, lane = tid & 63;
    int wc = wave;                        // (ch, ohh) selector
    int hi = lane >> 4, lsw = lane & 7, l15 = lane & 15;

    // R10 XCD-clustered decode: lin%8 = XCD = bq%8
    int lin = blockIdx.x;                 // [0, 2176)
    int r_ = lin & 7;
    int v_ = lin >> 3;                    // [0, 272)
    int ob = v_ & 7;
    int bq = r_ + ((v_ >> 3) << 3);       // [0, 272), bq%8 == r_

    int c0_ = counts[0], c1_ = counts[1], c2_ = counts[2],
        c3_ = counts[3], c4_ = counts[4], c5_ = counts[5];
    int s1 = (c0_ + 63) >> 6;
    int s2 = s1 + ((c1_ + 63) >> 6);
    int s3 = s2 + ((c2_ + 63) >> 6);
    int s4 = s3 + ((c3_ + 63) >> 6);
    int s5 = s4 + ((c4_ + 63) >> 6);
    int total = s5 + ((c5_ + 63) >> 6);
    if (bq >= total) return;
    int p, chunk, cnt, cA, cB;
    if      (bq < s1) { p = 0; chunk = bq;      cnt = c0_; cA = 0; cB = 1; }
    else if (bq < s2) { p = 1; chunk = bq - s1; cnt = c1_; cA = 0; cB = 2; }
    else if (bq < s3) { p = 2; chunk = bq - s2; cnt = c2_; cA = 0; cB = 3; }
    else if (bq < s4) { p = 3; chunk = bq - s3; cnt = c3_; cA = 1; cB = 2; }
    else if (bq < s5) { p = 4; chunk = bq - s4; cnt = c4_; cA = 1; cB = 3; }
    else              { p = 5; chunk = bq - s5; cnt = c5_; cA = 2; cB = 3; }
    int nvalid = min(64, cnt - chunk * 64);
    int rowbase = p * 16384 + chunk * 64;

    // A gather descriptors (R10): 128-B rows = 8 chunks; swizzle key = row&7
    int e0 = tid,        rA0 = e0 >> 3, gA0 = (e0 & 7) ^ (rA0 & 7);
    int e1 = 256 + tid,  rA1 = e1 >> 3, gA1 = (e1 & 7) ^ (rA1 & 7);
    int grA0 = rowList[rowbase + ((rA0 < nvalid) ? rA0 : 0)];
    int grA1 = rowList[rowbase + ((rA1 < nvalid) ? rA1 : 0)];
    const __hip_bfloat16* sA0 = featsB + (size_t)grA0 * 512 + gA0 * 8;
    const __hip_bfloat16* sA1 = featsB + (size_t)grA1 * 512 + gA1 * 8;
    int dA0 = e0 * 16, dA1 = e1 * 16;

    // B descriptors (R10): dest chunk e = j*256+tid -> dest row = j*32+t8 = src row
    int t8 = tid >> 3;
    int cswB = (tid & 7) ^ (t8 & 7);
    const __hip_bfloat16* sB_A = W3 + (size_t)(cA * 1024 + ob * 128 + t8) * 512 + cswB * 8;
    const __hip_bfloat16* sB_B = W3 + (size_t)(cB * 1024 + ob * 128 + t8) * 512 + cswB * 8;
    int dB = tid * 16;

    f32x4 acc[4][4];
#pragma unroll
    for (int m = 0; m < 4; ++m)
#pragma unroll
        for (int n = 0; n < 4; ++n)
            acc[m][n] = (f32x4){0.f, 0.f, 0.f, 0.f};

    // T14 staging registers (named -> static indexing, rule #20)
    short8 vA0, vA1, vB0, vB1, vB2, vB3, vB4, vB5, vB6, vB7;

#define LOADT(kt_) do { int ko_ = (kt_) * 64; \
        vA0 = *reinterpret_cast<const short8*>(sA0 + ko_); \
        vA1 = *reinterpret_cast<const short8*>(sA1 + ko_); \
        vB0 = *reinterpret_cast<const short8*>(sB_A + 0 * 16384 + ko_); \
        vB1 = *reinterpret_cast<const short8*>(sB_A + 1 * 16384 + ko_); \
        vB2 = *reinterpret_cast<const short8*>(sB_A + 2 * 16384 + ko_); \
        vB3 = *reinterpret_cast<const short8*>(sB_A + 3 * 16384 + ko_); \
        vB4 = *reinterpret_cast<const short8*>(sB_B + 0 * 16384 + ko_); \
        vB5 = *reinterpret_cast<const short8*>(sB_B + 1 * 16384 + ko_); \
        vB6 = *reinterpret_cast<const short8*>(sB_B + 2 * 16384 + ko_); \
        vB7 = *reinterpret_cast<const short8*>(sB_B + 3 * 16384 + ko_); \
    } while (0)

#define WRITET() do { \
        *reinterpret_cast<short8*>(As + dA0) = vA0; \
        *reinterpret_cast<short8*>(As + dA1) = vA1; \
        *reinterpret_cast<short8*>(Bs + dB +     0 * 4096) = vB0; \
        *reinterpret_cast<short8*>(Bs + dB +     1 * 4096) = vB1; \
        *reinterpret_cast<short8*>(Bs + dB +     2 * 4096) = vB2; \
        *reinterpret_cast<short8*>(Bs + dB +     3 * 4096) = vB3; \
        *reinterpret_cast<short8*>(Bs + 16384 + dB + 0 * 4096) = vB4; \
        *reinterpret_cast<short8*>(Bs + 16384 + dB + 1 * 4096) = vB5; \
        *reinterpret_cast<short8*>(Bs + 16384 + dB + 2 * 4096) = vB6; \
        *reinterpret_cast<short8*>(Bs + 16384 + dB + 3 * 4096) = vB7; \
    } while (0)

    // prologue: tile 0 -> regs -> LDS (one-time exposed latency)
    LOADT(0);
    WRITET();
    __syncthreads();

    for (int kt = 0; kt < 8; ++kt) {
        if (kt < 7) LOADT(kt + 1);        // issue early; lands by barrier below
#pragma unroll
        for (int kk = 0; kk < 2; ++kk) {
            short8 fa[4], fb[4];
#pragma unroll
            for (int m = 0; m < 4; ++m) {
                int row = m * 16 + l15;
                int chunkc = (kk * 4 + hi) ^ lsw;
                fa[m] = *reinterpret_cast<const short8*>(As + row * 128 + chunkc * 16);
            }
#pragma unroll
            for (int n = 0; n < 4; ++n) {
                int c2 = wc * 64 + n * 16 + l15;   // = ch*128 + ohh*64 + gate*16 + oi
                int chunkc = (kk * 4 + hi) ^ lsw;
                fb[n] = *reinterpret_cast<const short8*>(Bs + c2 * 128 + chunkc * 16);
            }
#pragma unroll
            for (int m = 0; m < 4; ++m)
#pragma unroll
                for (int n = 0; n < 4; ++n)
                    acc[m][n] = __builtin_amdgcn_mfma_f32_16x16x32_bf16(
                        fa[m], fb[n], acc[m][n], 0, 0, 0);
        }
        __syncthreads();                  // all reads done; vmcnt drain AFTER compute
        if (kt < 7) {
            WRITET();                     // regs -> LDS (next tile)
            __syncthreads();              // writes visible to all waves
        }
    }

    // ---- epilogue: per-wave LSTM (all 4 gates in-register), 2-way pair reduce ----
    int ohh = wc & 1;
    int ch  = wc >> 1;
    int cell = ch ? cB : cA;
    int og = ob * 32 + ohh * 16 + l15;    // global o in [0,256)
    float bb0 = bg[cell * 1024 + 0 * 256 + og];
    float bb1 = bg[cell * 1024 + 1 * 256 + og];
    float bb2 = bg[cell * 1024 + 2 * 256 + og];
    float bb3 = bg[cell * 1024 + 3 * 256 + og];

#define LSTM_BODY(STORE_OP) \
    _Pragma("unroll") \
    for (int m = 0; m < 4; ++m) { \
        _Pragma("unroll") \
        for (int reg = 0; reg < 4; ++reg) { \
            int r = m * 16 + hi * 4 + reg; \
            int grow = rowList[rowbase + ((r < nvalid) ? r : 0)]; \
            float gw = gates[(size_t)grow * 4 + cell]; \
            float iv = sigmoidf_(acc[m][0][reg] + bb0); \
            float jv = acc[m][1][reg] + bb1; \
            float fv = sigmoidf_(acc[m][2][reg] + bb2); \
            float ov = sigmoidf_(acc[m][3][reg] + bb3); \
            float cv = cin[(size_t)grow * 256 + og]; \
            float ncl = fv * cv + iv * tanhf_(jv); \
            float nhl = ov * tanhf_(ncl); \
            oAcc[r * 32 + ohh * 16 + l15] STORE_OP gw * nhl; \
            oAcc[2048 + r * 32 + ohh * 16 + l15] STORE_OP gw * ncl; \
        } \
    }

    if (ch == 0) { LSTM_BODY(=) }     // cell-A waves cover all [2][64][32] slots
    __syncthreads();
    if (ch == 1) { LSTM_BODY(+=) }    // cell-B waves accumulate
    __syncthreads();
#undef LSTM_BODY
#undef LOADT
#undef WRITET

    {
        int r = tid >> 2, q = tid & 3;
        if (r < nvalid) {
            int grow = rowList[rowbase + r];
            size_t obase = (size_t)grow * 256 + ob * 32 + q * 8;
            *(float4*)&out[obase]     = *(float4*)&oAcc[r * 32 + q * 8];
            *(float4*)&out[obase + 4] = *(float4*)&oAcc[r * 32 + q * 8 + 4];
            *(float4*)&out[(size_t)NB * 256 + obase]     = *(float4*)&oAcc[2048 + r * 32 + q * 8];
            *(float4*)&out[(size_t)NB * 256 + obase + 4] = *(float4*)&oAcc[2048 + r * 32 + q * 8 + 4];
        }
    }
}

extern "C" void kernel_launch(void* const* d_in, const int* in_sizes, int n_in,
                              void* d_out, int out_size, void* d_ws, size_t ws_size,
                              hipStream_t stream) {
    const float* x  = (const float*)d_in[0];
    const float* c  = (const float*)d_in[1];
    const float* h  = (const float*)d_in[2];
    const float* Wg = (const float*)d_in[3];
    const float* bg = (const float*)d_in[4];
    const float* Wc = (const float*)d_in[5];
    const float* bc = (const float*)d_in[6];
    float* out = (float*)d_out;

    const size_t featsB_bytes = (size_t)NB * DD * 2;        // 16.78 MB
    const size_t w3_bytes     = (size_t)NCOLS * DD * 2;     // 4.19 MB
    const size_t gates_bytes  = (size_t)NB * 4 * 4;         // 0.26 MB
    const size_t counts_bytes = 256;
    const size_t rlist_bytes  = (size_t)6 * 16384 * 4;      // 0.39 MB
    if (ws_size < featsB_bytes + w3_bytes + gates_bytes + counts_bytes + rlist_bytes)
        return;

    char* ws = (char*)d_ws;
    __hip_bfloat16* featsB = (__hip_bfloat16*)ws;
    __hip_bfloat16* W3     = (__hip_bfloat16*)(ws + featsB_bytes);
    float*          gatesW = (float*)(ws + featsB_bytes + w3_bytes);
    int*            counts = (int*)(ws + featsB_bytes + w3_bytes + gates_bytes);
    int*            rowLst = (int*)(ws + featsB_bytes + w3_bytes + gates_bytes + counts_bytes);

    hipMemsetAsync(counts, 0, 32, stream);
    k_pre<<<dim3(5120), dim3(256), 0, stream>>>(x, h, Wc, bc, Wg, featsB, gatesW, W3);
    k_bucket<<<dim3(64), dim3(256), 0, stream>>>(gatesW, counts, rowLst);
    // 2176 = 8 XCD-residues x 34 chunk-groups x 8 obs; blocks with bq>=total exit
    k_main<<<dim3(2176), dim3(256), 0, stream>>>(featsB, W3, c, gatesW, bg,
                                                 counts, rowLst, out);
}

// Round 14
// 123.083 us; speedup vs baseline: 1.0753x; 1.0305x over previous
//
#include <hip/hip_runtime.h>
#include <hip/hip_bf16.h>

// Problem constants
#define NB 16384      // batch rows
#define DD 512        // IN+OUT
#define NCOLS 4096    // 4*OUT*NCELL

typedef __attribute__((ext_vector_type(8))) short short8;
typedef __attribute__((ext_vector_type(4))) float f32x4;

__device__ __forceinline__ float sigmoidf_(float x) {
    return 1.f / (1.f + __expf(-x));
}
__device__ __forceinline__ float tanhf_(float x) {
    float e = __expf(-2.f * fabsf(x));      // in (0,1], no overflow
    float t = (1.f - e) / (1.f + e);
    return copysignf(t, x);
}

#define GLOAD_LDS16(g, l) __builtin_amdgcn_global_load_lds( \
    (__attribute__((address_space(1))) void*)(g), \
    (__attribute__((address_space(3))) void*)(l), 16, 0, 0)

// ---------------- P1 (fused): feats->bf16 + ctrl gates | W_gates repack to W4 ----
// W4 layout (R8-proven): chunk c = (((cell*8+ob)*8 + rowg)*16 + kkg)*64 + lane,
// rowg = oh*4 + gate, chunk holds k = kkg*32 + (lane>>4)*8 .. +8 of column
// (cell,gate,ob,oh,oi=lane&15). In k_main a wave's B-fragment load is then
// uniform_base + lane*16 -> one fully-coalesced 1KB wave load.
__global__ void k_pre(const float* __restrict__ x, const float* __restrict__ h,
                      const float* __restrict__ Wc, const float* __restrict__ bc,
                      const float* __restrict__ Wg,
                      __hip_bfloat16* __restrict__ featsB, float* __restrict__ gates,
                      __hip_bfloat16* __restrict__ W4) {
    int bid = blockIdx.x;
    if (bid < 4096) {
        int wave = bid * 4 + (threadIdx.x >> 6);  // == row
        int lane = threadIdx.x & 63;
        int row = wave;
        int k0 = lane * 8;
        const float* src = (k0 < 256) ? (x + (size_t)row * 256 + k0)
                                      : (h + (size_t)row * 256 + k0 - 256);
        float4 f0 = ((const float4*)src)[0];
        float4 f1 = ((const float4*)src)[1];
        float fv[8] = {f0.x, f0.y, f0.z, f0.w, f1.x, f1.y, f1.z, f1.w};
        __hip_bfloat16 tmp[8];
#pragma unroll
        for (int j = 0; j < 8; ++j) tmp[j] = __float2bfloat16(fv[j]);
        *reinterpret_cast<short8*>(featsB + (size_t)row * 512 + k0) =
            *reinterpret_cast<short8*>(tmp);
        float acc[4] = {0.f, 0.f, 0.f, 0.f};
#pragma unroll
        for (int j = 0; j < 8; ++j) {
            float4 w = ((const float4*)Wc)[k0 + j];
            acc[0] += fv[j] * w.x; acc[1] += fv[j] * w.y;
            acc[2] += fv[j] * w.z; acc[3] += fv[j] * w.w;
        }
#pragma unroll
        for (int off = 32; off; off >>= 1) {
#pragma unroll
            for (int c = 0; c < 4; ++c) acc[c] += __shfl_xor(acc[c], off);
        }
        if (lane == 0) {
            float l[4];
#pragma unroll
            for (int c = 0; c < 4; ++c) l[c] = acc[c] + bc[c];
            int i1 = 0;
#pragma unroll
            for (int c = 1; c < 4; ++c) if (l[c] > l[i1]) i1 = c;  // ties -> lowest
            int i2 = -1;
#pragma unroll
            for (int c = 0; c < 4; ++c)
                if (c != i1 && (i2 < 0 || l[c] > l[i2])) i2 = c;
            float e = __expf(l[i2] - l[i1]);   // <= 1
            float p1 = 1.f / (1.f + e);
            float p2 = e / (1.f + e);
            float g[4] = {0.f, 0.f, 0.f, 0.f};
            g[i1] = p1; g[i2] = p2;
            float4 gv; gv.x = g[0]; gv.y = g[1]; gv.z = g[2]; gv.w = g[3];
            *(float4*)(gates + (size_t)row * 4) = gv;
        }
    } else {
        int c = (bid - 4096) * 256 + threadIdx.x;   // chunk id, 0..262143
        int lane = c & 63;
        int kkg  = (c >> 6) & 15;
        int rowg = (c >> 10) & 7;
        int ob   = (c >> 13) & 7;
        int cell = c >> 16;
        int oi = lane & 15, hi = lane >> 4;
        int gate = rowg & 3, oh = rowg >> 2;
        int col = cell * 1024 + gate * 256 + ob * 32 + oh * 16 + oi;
        int kb = kkg * 32 + hi * 8;
        __hip_bfloat16 tmp[8];
#pragma unroll
        for (int j = 0; j < 8; ++j)
            tmp[j] = __float2bfloat16(Wg[(size_t)(kb + j) * 4096 + col]);
        *reinterpret_cast<short8*>(W4 + (size_t)c * 8) = *reinterpret_cast<short8*>(tmp);
    }
}

// ---------------- P2: bucket rows by active cell-pair (wave-aggregated atomics) ----
__global__ void k_bucket(const float* __restrict__ gates, int* __restrict__ counts,
                         int* __restrict__ rowList) {
    int row = blockIdx.x * 256 + threadIdx.x;
    int lane = threadIdx.x & 63;
    float4 g = *(const float4*)(gates + (size_t)row * 4);
    int i1 = 0; float m1 = g.x;
    if (g.y > m1) { m1 = g.y; i1 = 1; }
    if (g.z > m1) { m1 = g.z; i1 = 2; }
    if (g.w > m1) { m1 = g.w; i1 = 3; }
    int i2 = -1; float m2 = -1.f;
    if (i1 != 0)             { m2 = g.x; i2 = 0; }
    if (i1 != 1 && g.y > m2) { m2 = g.y; i2 = 1; }
    if (i1 != 2 && g.z > m2) { m2 = g.z; i2 = 2; }
    if (i1 != 3 && g.w > m2) { m2 = g.w; i2 = 3; }
    int a = min(i1, i2), b = max(i1, i2);
    int pid = (a == 0) ? (b - 1) : (a == 1) ? (1 + b) : 5;
#pragma unroll
    for (int q = 0; q < 6; ++q) {
        unsigned long long m = __ballot(pid == q);   // uniform execution
        if (pid == q) {
            int leader = __ffsll((long long)m) - 1;
            int base = 0;
            if (lane == leader) base = atomicAdd(counts + q, __popcll(m));
            base = __shfl(base, leader);
            int prefix = __popcll(m & ((1ull << lane) - 1ull));
            rowList[q * 16384 + base + prefix] = row;
        }
    }
}

// ---------------- Main: pair-bucketed GEMM, B-in-register + A-LDS-dbuf ----------
// Partition = R10 (256 thr / 4 waves, 64 rows x 256 cols, one ob). Structural
// change: B is WAVE-PRIVATE in this partition, so it skips LDS entirely — each
// fragment is a contiguous 1KB wave load from W4 into registers (R8-proven
// layout). Only A (shared by all 4 waves) goes through LDS, double-buffered
// 2x8KB via global_load_lds. ONE __syncthreads per tile; its implicit vmcnt(0)
// drain is covered by the 16-MFMA compute phase. LDS traffic/tile: 104->40 KB.
// Full unroll -> all reg-array indices static (rule #20). No manual vmcnt.
__launch_bounds__(256, 3)
__global__ void k_main(const __hip_bfloat16* __restrict__ featsB,
                       const __hip_bfloat16* __restrict__ W4,
                       const float* __restrict__ cin,
                       const float* __restrict__ gates,
                       const float* __restrict__ bg,
                       const int* __restrict__ counts,
                       const int* __restrict__ rowList,
                       float* __restrict__ out) {
    __shared__ char smem[16384];          // As[2][8192] ; oAcc 16K aliases
    float* oAcc = (float*)smem;           // [2][64][32] f32 (epilogue)

    int tid = threadIdx.x;
    int wave = tid >> 6, lane = tid & 63;
    int wc = wave;                        // (ch, ohh) selector
    int hi = lane >> 4, lsw = lane & 7, l15 = lane & 15;

    // R10 XCD-clustered decode: lin%8 = XCD = bq%8
    int lin = blockIdx.x;                 // [0, 2176)
    int r_ = lin & 7;
    int v_ = lin >> 3;                    // [0, 272)
    int ob = v_ & 7;
    int bq = r_ + ((v_ >> 3) << 3);       // [0, 272), bq%8 == r_

    int c0_ = counts[0], c1_ = counts[1], c2_ = counts[2],
        c3_ = counts[3], c4_ = counts[4], c5_ = counts[5];
    int s1 = (c0_ + 63) >> 6;
    int s2 = s1 + ((c1_ + 63) >> 6);
    int s3 = s2 + ((c2_ + 63) >> 6);
    int s4 = s3 + ((c3_ + 63) >> 6);
    int s5 = s4 + ((c4_ + 63) >> 6);
    int total = s5 + ((c5_ + 63) >> 6);
    if (bq >= total) return;
    int p, chunk, cnt, cA, cB;
    if      (bq < s1) { p = 0; chunk = bq;      cnt = c0_; cA = 0; cB = 1; }
    else if (bq < s2) { p = 1; chunk = bq - s1; cnt = c1_; cA = 0; cB = 2; }
    else if (bq < s3) { p = 2; chunk = bq - s2; cnt = c2_; cA = 0; cB = 3; }
    else if (bq < s4) { p = 3; chunk = bq - s3; cnt = c3_; cA = 1; cB = 2; }
    else if (bq < s5) { p = 4; chunk = bq - s4; cnt = c4_; cA = 1; cB = 3; }
    else              { p = 5; chunk = bq - s5; cnt = c5_; cA = 2; cB = 3; }
    int nvalid = min(64, cnt - chunk * 64);
    int rowbase = p * 16384 + chunk * 64;

    int ohh = wc & 1;
    int ch  = wc >> 1;
    int cell = ch ? cB : cA;

    // A gather descriptors (R10-proven): 128-B rows = 8 chunks; swizzle key = row&7
    int e0 = tid,        rA0 = e0 >> 3, gA0 = (e0 & 7) ^ (rA0 & 7);
    int e1 = 256 + tid,  rA1 = e1 >> 3, gA1 = (e1 & 7) ^ (rA1 & 7);
    int grA0 = rowList[rowbase + ((rA0 < nvalid) ? rA0 : 0)];
    int grA1 = rowList[rowbase + ((rA1 < nvalid) ? rA1 : 0)];
    const __hip_bfloat16* sA0 = featsB + (size_t)grA0 * 512 + gA0 * 8;
    const __hip_bfloat16* sA1 = featsB + (size_t)grA1 * 512 + gA1 * 8;
    int dA0 = e0 * 16, dA1 = e1 * 16;

    // B wave base in W4 (R8-proven mapping): fragment (n, kkg) at
    // base + n*8192 + kkg*512 elements; per-lane footprint = lane*8 (coalesced).
    const __hip_bfloat16* bBw =
        W4 + ((size_t)(cell * 8 + ob) * 128 + ohh * 64) * 512 + lane * 8;

    f32x4 acc[4][4];
#pragma unroll
    for (int m = 0; m < 4; ++m)
#pragma unroll
        for (int n = 0; n < 4; ++n)
            acc[m][n] = (f32x4){0.f, 0.f, 0.f, 0.f};

    short8 br[2][4][2];                   // [tile parity][n][kk] — static after unroll

#define STAGE_A(kt_, buf_) do { \
        GLOAD_LDS16(sA0 + (kt_) * 64, smem + (buf_) * 8192 + dA0); \
        GLOAD_LDS16(sA1 + (kt_) * 64, smem + (buf_) * 8192 + dA1); \
    } while (0)
#define LOAD_B(pb_, kt_) do { \
        _Pragma("unroll") \
        for (int n_ = 0; n_ < 4; ++n_) \
            _Pragma("unroll") \
            for (int kk_ = 0; kk_ < 2; ++kk_) \
                br[pb_][n_][kk_] = *reinterpret_cast<const short8*>( \
                    bBw + n_ * 8192 + ((kt_) * 2 + kk_) * 512); \
    } while (0)

    // prologue: tile 0 -> A buf 0 + B regs[0]
    STAGE_A(0, 0);
    LOAD_B(0, 0);
    __syncthreads();                      // A(0) in LDS (vmcnt0 also lands B(0))

#pragma unroll
    for (int kt = 0; kt < 8; ++kt) {
        const int buf = kt & 1;
        if (kt < 7) {                     // issue next tile's loads BEFORE compute
            STAGE_A(kt + 1, buf ^ 1);
            LOAD_B(buf ^ 1, kt + 1);
        }
        const char* Ab = smem + buf * 8192;
#pragma unroll
        for (int kk = 0; kk < 2; ++kk) {
            short8 fa[4];
#pragma unroll
            for (int m = 0; m < 4; ++m) {
                int row = m * 16 + l15;
                int chunkc = (kk * 4 + hi) ^ lsw;
                fa[m] = *reinterpret_cast<const short8*>(Ab + row * 128 + chunkc * 16);
            }
#pragma unroll
            for (int m = 0; m < 4; ++m)
#pragma unroll
                for (int n = 0; n < 4; ++n)
                    acc[m][n] = __builtin_amdgcn_mfma_f32_16x16x32_bf16(
                        fa[m], br[buf][n][kk], acc[m][n], 0, 0, 0);
        }
        __syncthreads();  // reads of buf done; vmcnt(0) drain covered by compute
    }
#undef STAGE_A
#undef LOAD_B

    // ---- epilogue: per-wave LSTM (all 4 gates in-register), 2-way pair reduce ----
    int og = ob * 32 + ohh * 16 + l15;    // global o in [0,256)
    float bb0 = bg[cell * 1024 + 0 * 256 + og];
    float bb1 = bg[cell * 1024 + 1 * 256 + og];
    float bb2 = bg[cell * 1024 + 2 * 256 + og];
    float bb3 = bg[cell * 1024 + 3 * 256 + og];

#define LSTM_BODY(STORE_OP) \
    _Pragma("unroll") \
    for (int m = 0; m < 4; ++m) { \
        _Pragma("unroll") \
        for (int reg = 0; reg < 4; ++reg) { \
            int r = m * 16 + hi * 4 + reg; \
            int grow = rowList[rowbase + ((r < nvalid) ? r : 0)]; \
            float gw = gates[(size_t)grow * 4 + cell]; \
            float iv = sigmoidf_(acc[m][0][reg] + bb0); \
            float jv = acc[m][1][reg] + bb1; \
            float fv = sigmoidf_(acc[m][2][reg] + bb2); \
            float ov = sigmoidf_(acc[m][3][reg] + bb3); \
            float cv = cin[(size_t)grow * 256 + og]; \
            float ncl = fv * cv + iv * tanhf_(jv); \
            float nhl = ov * tanhf_(ncl); \
            oAcc[r * 32 + ohh * 16 + l15] STORE_OP gw * nhl; \
            oAcc[2048 + r * 32 + ohh * 16 + l15] STORE_OP gw * ncl; \
        } \
    }

    if (ch == 0) { LSTM_BODY(=) }     // cell-A waves cover all [2][64][32] slots
    __syncthreads();
    if (ch == 1) { LSTM_BODY(+=) }    // cell-B waves accumulate
    __syncthreads();
#undef LSTM_BODY

    {
        int r = tid >> 2, q = tid & 3;
        if (r < nvalid) {
            int grow = rowList[rowbase + r];
            size_t obase = (size_t)grow * 256 + ob * 32 + q * 8;
            *(float4*)&out[obase]     = *(float4*)&oAcc[r * 32 + q * 8];
            *(float4*)&out[obase + 4] = *(float4*)&oAcc[r * 32 + q * 8 + 4];
            *(float4*)&out[(size_t)NB * 256 + obase]     = *(float4*)&oAcc[2048 + r * 32 + q * 8];
            *(float4*)&out[(size_t)NB * 256 + obase + 4] = *(float4*)&oAcc[2048 + r * 32 + q * 8 + 4];
        }
    }
}

extern "C" void kernel_launch(void* const* d_in, const int* in_sizes, int n_in,
                              void* d_out, int out_size, void* d_ws, size_t ws_size,
                              hipStream_t stream) {
    const float* x  = (const float*)d_in[0];
    const float* c  = (const float*)d_in[1];
    const float* h  = (const float*)d_in[2];
    const float* Wg = (const float*)d_in[3];
    const float* bg = (const float*)d_in[4];
    const float* Wc = (const float*)d_in[5];
    const float* bc = (const float*)d_in[6];
    float* out = (float*)d_out;

    const size_t featsB_bytes = (size_t)NB * DD * 2;        // 16.78 MB
    const size_t w4_bytes     = (size_t)NCOLS * DD * 2;     // 4.19 MB
    const size_t gates_bytes  = (size_t)NB * 4 * 4;         // 0.26 MB
    const size_t counts_bytes = 256;
    const size_t rlist_bytes  = (size_t)6 * 16384 * 4;      // 0.39 MB
    if (ws_size < featsB_bytes + w4_bytes + gates_bytes + counts_bytes + rlist_bytes)
        return;

    char* ws = (char*)d_ws;
    __hip_bfloat16* featsB = (__hip_bfloat16*)ws;
    __hip_bfloat16* W4     = (__hip_bfloat16*)(ws + featsB_bytes);
    float*          gatesW = (float*)(ws + featsB_bytes + w4_bytes);
    int*            counts = (int*)(ws + featsB_bytes + w4_bytes + gates_bytes);
    int*            rowLst = (int*)(ws + featsB_bytes + w4_bytes + gates_bytes + counts_bytes);

    hipMemsetAsync(counts, 0, 32, stream);
    k_pre<<<dim3(5120), dim3(256), 0, stream>>>(x, h, Wc, bc, Wg, featsB, gatesW, W4);
    k_bucket<<<dim3(64), dim3(256), 0, stream>>>(gatesW, counts, rowLst);
    // 2176 = 8 XCD-residues x 34 chunk-groups x 8 obs; blocks with bq>=total exit
    k_main<<<dim3(2176), dim3(256), 0, stream>>>(featsB, W4, c, gatesW, bg,
                                                 counts, rowLst, out);
}

// Round 15
// 115.818 us; speedup vs baseline: 1.1427x; 1.0627x over previous
//
#include <hip/hip_runtime.h>
#include <hip/hip_bf16.h>

// Problem constants
#define NB 16384      // batch rows
#define DD 512        // IN+OUT
#define NCOLS 4096    // 4*OUT*NCELL

typedef __attribute__((ext_vector_type(8))) short short8;
typedef __attribute__((ext_vector_type(4))) float f32x4;

__device__ __forceinline__ float sigmoidf_(float x) {
    return 1.f / (1.f + __expf(-x));
}
__device__ __forceinline__ float tanhf_(float x) {
    float e = __expf(-2.f * fabsf(x));      // in (0,1], no overflow
    float t = (1.f - e) / (1.f + e);
    return copysignf(t, x);
}

#define GLOAD_LDS16(g, l) __builtin_amdgcn_global_load_lds( \
    (__attribute__((address_space(1))) void*)(g), \
    (__attribute__((address_space(3))) void*)(l), 16, 0, 0)

// ---------------- P1 (fused): feats->bf16 + ctrl gates | W_gates repack to W4 ----
// W4 layout (R8-proven): chunk c = (((cell*8+ob)*8 + rowg)*16 + kkg)*64 + lane,
// rowg = oh*4 + gate; chunk holds k = kkg*32 + (lane>>4)*8 .. +8 of column
// (cell,gate,ob,oh,oi=lane&15). A wave's B-fragment load in k_main is then
// uniform_base + lane*16 -> one fully-coalesced 1KB wave load.
__global__ void k_pre(const float* __restrict__ x, const float* __restrict__ h,
                      const float* __restrict__ Wc, const float* __restrict__ bc,
                      const float* __restrict__ Wg,
                      __hip_bfloat16* __restrict__ featsB, float* __restrict__ gates,
                      __hip_bfloat16* __restrict__ W4) {
    int bid = blockIdx.x;
    if (bid < 4096) {
        int wave = bid * 4 + (threadIdx.x >> 6);  // == row
        int lane = threadIdx.x & 63;
        int row = wave;
        int k0 = lane * 8;
        const float* src = (k0 < 256) ? (x + (size_t)row * 256 + k0)
                                      : (h + (size_t)row * 256 + k0 - 256);
        float4 f0 = ((const float4*)src)[0];
        float4 f1 = ((const float4*)src)[1];
        float fv[8] = {f0.x, f0.y, f0.z, f0.w, f1.x, f1.y, f1.z, f1.w};
        __hip_bfloat16 tmp[8];
#pragma unroll
        for (int j = 0; j < 8; ++j) tmp[j] = __float2bfloat16(fv[j]);
        *reinterpret_cast<short8*>(featsB + (size_t)row * 512 + k0) =
            *reinterpret_cast<short8*>(tmp);
        float acc[4] = {0.f, 0.f, 0.f, 0.f};
#pragma unroll
        for (int j = 0; j < 8; ++j) {
            float4 w = ((const float4*)Wc)[k0 + j];
            acc[0] += fv[j] * w.x; acc[1] += fv[j] * w.y;
            acc[2] += fv[j] * w.z; acc[3] += fv[j] * w.w;
        }
#pragma unroll
        for (int off = 32; off; off >>= 1) {
#pragma unroll
            for (int c = 0; c < 4; ++c) acc[c] += __shfl_xor(acc[c], off);
        }
        if (lane == 0) {
            float l[4];
#pragma unroll
            for (int c = 0; c < 4; ++c) l[c] = acc[c] + bc[c];
            int i1 = 0;
#pragma unroll
            for (int c = 1; c < 4; ++c) if (l[c] > l[i1]) i1 = c;  // ties -> lowest
            int i2 = -1;
#pragma unroll
            for (int c = 0; c < 4; ++c)
                if (c != i1 && (i2 < 0 || l[c] > l[i2])) i2 = c;
            float e = __expf(l[i2] - l[i1]);   // <= 1
            float p1 = 1.f / (1.f + e);
            float p2 = e / (1.f + e);
            float g[4] = {0.f, 0.f, 0.f, 0.f};
            g[i1] = p1; g[i2] = p2;
            float4 gv; gv.x = g[0]; gv.y = g[1]; gv.z = g[2]; gv.w = g[3];
            *(float4*)(gates + (size_t)row * 4) = gv;
        }
    } else {
        int c = (bid - 4096) * 256 + threadIdx.x;   // chunk id, 0..262143
        int lane = c & 63;
        int kkg  = (c >> 6) & 15;
        int rowg = (c >> 10) & 7;
        int ob   = (c >> 13) & 7;
        int cell = c >> 16;
        int oi = lane & 15, hi = lane >> 4;
        int gate = rowg & 3, oh = rowg >> 2;
        int col = cell * 1024 + gate * 256 + ob * 32 + oh * 16 + oi;
        int kb = kkg * 32 + hi * 8;
        __hip_bfloat16 tmp[8];
#pragma unroll
        for (int j = 0; j < 8; ++j)
            tmp[j] = __float2bfloat16(Wg[(size_t)(kb + j) * 4096 + col]);
        *reinterpret_cast<short8*>(W4 + (size_t)c * 8) = *reinterpret_cast<short8*>(tmp);
    }
}

// ---------------- P2: bucket rows by active cell-pair (wave-aggregated atomics) ----
__global__ void k_bucket(const float* __restrict__ gates, int* __restrict__ counts,
                         int* __restrict__ rowList) {
    int row = blockIdx.x * 256 + threadIdx.x;
    int lane = threadIdx.x & 63;
    float4 g = *(const float4*)(gates + (size_t)row * 4);
    int i1 = 0; float m1 = g.x;
    if (g.y > m1) { m1 = g.y; i1 = 1; }
    if (g.z > m1) { m1 = g.z; i1 = 2; }
    if (g.w > m1) { m1 = g.w; i1 = 3; }
    int i2 = -1; float m2 = -1.f;
    if (i1 != 0)             { m2 = g.x; i2 = 0; }
    if (i1 != 1 && g.y > m2) { m2 = g.y; i2 = 1; }
    if (i1 != 2 && g.z > m2) { m2 = g.z; i2 = 2; }
    if (i1 != 3 && g.w > m2) { m2 = g.w; i2 = 3; }
    int a = min(i1, i2), b = max(i1, i2);
    int pid = (a == 0) ? (b - 1) : (a == 1) ? (1 + b) : 5;
#pragma unroll
    for (int q = 0; q < 6; ++q) {
        unsigned long long m = __ballot(pid == q);   // uniform execution
        if (pid == q) {
            int leader = __ffsll((long long)m) - 1;
            int base = 0;
            if (lane == leader) base = atomicAdd(counts + q, __popcll(m));
            base = __shfl(base, leader);
            int prefix = __popcll(m & ((1ull << lane) - 1ull));
            rowList[q * 16384 + base + prefix] = row;
        }
    }
}

// ---------------- Main: pair-bucketed GEMM, B-in-register + A-LDS-dbuf ----------
// K-loop byte-identical to R13. NEW (T14 applied to the EPILOGUE): the chunk's
// cin slice (64x32 f32, 8KB) and gates slice (64x4, 1KB) are staged into LDS by
// global_load_lds issued at block START — they land under the K-loop's first
// barrier, so the epilogue's 16-iteration gather chain (previously ~400-600cy
// L2/L3 latency per dependent load) becomes LDS-latency reads.
__launch_bounds__(256, 3)
__global__ void k_main(const __hip_bfloat16* __restrict__ featsB,
                       const __hip_bfloat16* __restrict__ W4,
                       const float* __restrict__ cin,
                       const float* __restrict__ gates,
                       const float* __restrict__ bg,
                       const int* __restrict__ counts,
                       const int* __restrict__ rowList,
                       float* __restrict__ out) {
    __shared__ char smem[25600];          // A[2][8192] | cinS 8K | gatesS 1K
    float* oAcc  = (float*)smem;          // [2][64][32] f32 — aliases A bufs only
    float* cinS  = (float*)(smem + 16384);   // [64][32]
    float* gatesS = (float*)(smem + 24576);  // [64][4]

    int tid = threadIdx.x;
    int wave = tid >> 6, lane = tid & 63;
    int wc = wave;                        // (ch, ohh) selector
    int hi = lane >> 4, lsw = lane & 7, l15 = lane & 15;

    // R10 XCD-clustered decode: lin%8 = XCD = bq%8
    int lin = blockIdx.x;                 // [0, 2176)
    int r_ = lin & 7;
    int v_ = lin >> 3;                    // [0, 272)
    int ob = v_ & 7;
    int bq = r_ + ((v_ >> 3) << 3);       // [0, 272), bq%8 == r_

    int c0_ = counts[0], c1_ = counts[1], c2_ = counts[2],
        c3_ = counts[3], c4_ = counts[4], c5_ = counts[5];
    int s1 = (c0_ + 63) >> 6;
    int s2 = s1 + ((c1_ + 63) >> 6);
    int s3 = s2 + ((c2_ + 63) >> 6);
    int s4 = s3 + ((c3_ + 63) >> 6);
    int s5 = s4 + ((c4_ + 63) >> 6);
    int total = s5 + ((c5_ + 63) >> 6);
    if (bq >= total) return;
    int p, chunk, cnt, cA, cB;
    if      (bq < s1) { p = 0; chunk = bq;      cnt = c0_; cA = 0; cB = 1; }
    else if (bq < s2) { p = 1; chunk = bq - s1; cnt = c1_; cA = 0; cB = 2; }
    else if (bq < s3) { p = 2; chunk = bq - s2; cnt = c2_; cA = 0; cB = 3; }
    else if (bq < s4) { p = 3; chunk = bq - s3; cnt = c3_; cA = 1; cB = 2; }
    else if (bq < s5) { p = 4; chunk = bq - s4; cnt = c4_; cA = 1; cB = 3; }
    else              { p = 5; chunk = bq - s5; cnt = c5_; cA = 2; cB = 3; }
    int nvalid = min(64, cnt - chunk * 64);
    int rowbase = p * 16384 + chunk * 64;

    int ohh = wc & 1;
    int ch  = wc >> 1;
    int cell = ch ? cB : cA;

    // A gather descriptors (R10-proven): 128-B rows = 8 chunks; swizzle key = row&7
    int e0 = tid,        rA0 = e0 >> 3, gA0 = (e0 & 7) ^ (rA0 & 7);
    int e1 = 256 + tid,  rA1 = e1 >> 3, gA1 = (e1 & 7) ^ (rA1 & 7);
    int grA0 = rowList[rowbase + ((rA0 < nvalid) ? rA0 : 0)];
    int grA1 = rowList[rowbase + ((rA1 < nvalid) ? rA1 : 0)];
    const __hip_bfloat16* sA0 = featsB + (size_t)grA0 * 512 + gA0 * 8;
    const __hip_bfloat16* sA1 = featsB + (size_t)grA1 * 512 + gA1 * 8;
    int dA0 = e0 * 16, dA1 = e1 * 16;

    // B wave base in W4 (R8-proven mapping)
    const __hip_bfloat16* bBw =
        W4 + ((size_t)(cell * 8 + ob) * 128 + ohh * 64) * 512 + lane * 8;

    f32x4 acc[4][4];
#pragma unroll
    for (int m = 0; m < 4; ++m)
#pragma unroll
        for (int n = 0; n < 4; ++n)
            acc[m][n] = (f32x4){0.f, 0.f, 0.f, 0.f};

    short8 br[2][4][2];                   // [buf parity][n][kk] — static after unroll

#define STAGE_A(kt_, buf_) do { \
        GLOAD_LDS16(sA0 + (kt_) * 64, smem + (buf_) * 8192 + dA0); \
        GLOAD_LDS16(sA1 + (kt_) * 64, smem + (buf_) * 8192 + dA1); \
    } while (0)
#define LOAD_B(pb_, kt_) do { \
        _Pragma("unroll") \
        for (int n_ = 0; n_ < 4; ++n_) \
            _Pragma("unroll") \
            for (int kk_ = 0; kk_ < 2; ++kk_) \
                br[pb_][n_][kk_] = *reinterpret_cast<const short8*>( \
                    bBw + n_ * 8192 + ((kt_) * 2 + kk_) * 512); \
    } while (0)

    // prologue: tile 0 + EPILOGUE OPERAND PREFETCH (cin/gates -> LDS; they sit
    // in LDS untouched until after the K-loop)
    STAGE_A(0, 0);
    {
        // cin slice: 512 16B-chunks (2/thread): chunk e -> row e>>3, qword e&7
        int ec0 = tid,       rc0 = ec0 >> 3, qc0 = ec0 & 7;
        int ec1 = 256 + tid, rc1 = ec1 >> 3, qc1 = ec1 & 7;
        int gr0 = rowList[rowbase + ((rc0 < nvalid) ? rc0 : 0)];
        int gr1 = rowList[rowbase + ((rc1 < nvalid) ? rc1 : 0)];
        GLOAD_LDS16(cin + (size_t)gr0 * 256 + ob * 32 + qc0 * 4,
                    (char*)cinS + ec0 * 16);
        GLOAD_LDS16(cin + (size_t)gr1 * 256 + ob * 32 + qc1 * 4,
                    (char*)cinS + ec1 * 16);
        // gates slice: 64 16B-chunks, wave 0 only (dest = base + lane*16)
        if (tid < 64) {
            int gr = rowList[rowbase + ((tid < nvalid) ? tid : 0)];
            GLOAD_LDS16(gates + (size_t)gr * 4, (char*)gatesS + tid * 16);
        }
    }
    LOAD_B(0, 0);
    __syncthreads();                      // drains: A(0), cin, gates in LDS

#pragma unroll
    for (int kt = 0; kt < 8; ++kt) {
        const int buf = kt & 1;
        if (kt < 7) {                     // issue next tile's loads BEFORE compute
            STAGE_A(kt + 1, buf ^ 1);
            LOAD_B(buf ^ 1, kt + 1);
        }
        const char* Ab = smem + buf * 8192;
#pragma unroll
        for (int kk = 0; kk < 2; ++kk) {
            short8 fa[4];
#pragma unroll
            for (int m = 0; m < 4; ++m) {
                int row = m * 16 + l15;
                int chunkc = (kk * 4 + hi) ^ lsw;
                fa[m] = *reinterpret_cast<const short8*>(Ab + row * 128 + chunkc * 16);
            }
#pragma unroll
            for (int m = 0; m < 4; ++m)
#pragma unroll
                for (int n = 0; n < 4; ++n)
                    acc[m][n] = __builtin_amdgcn_mfma_f32_16x16x32_bf16(
                        fa[m], br[buf][n][kk], acc[m][n], 0, 0, 0);
        }
        __syncthreads();  // reads of buf done; vmcnt(0) drain covered by compute
    }
#undef STAGE_A
#undef LOAD_B

    // ---- epilogue: all operands in LDS/registers — no global gathers ----
    int og = ob * 32 + ohh * 16 + l15;    // global o in [0,256)
    float bb0 = bg[cell * 1024 + 0 * 256 + og];
    float bb1 = bg[cell * 1024 + 1 * 256 + og];
    float bb2 = bg[cell * 1024 + 2 * 256 + og];
    float bb3 = bg[cell * 1024 + 3 * 256 + og];

#define LSTM_BODY(STORE_OP) \
    _Pragma("unroll") \
    for (int m = 0; m < 4; ++m) { \
        _Pragma("unroll") \
        for (int reg = 0; reg < 4; ++reg) { \
            int r = m * 16 + hi * 4 + reg; \
            float gw = gatesS[r * 4 + cell]; \
            float iv = sigmoidf_(acc[m][0][reg] + bb0); \
            float jv = acc[m][1][reg] + bb1; \
            float fv = sigmoidf_(acc[m][2][reg] + bb2); \
            float ov = sigmoidf_(acc[m][3][reg] + bb3); \
            float cv = cinS[r * 32 + ohh * 16 + l15]; \
            float ncl = fv * cv + iv * tanhf_(jv); \
            float nhl = ov * tanhf_(ncl); \
            oAcc[r * 32 + ohh * 16 + l15] STORE_OP gw * nhl; \
            oAcc[2048 + r * 32 + ohh * 16 + l15] STORE_OP gw * ncl; \
        } \
    }

    if (ch == 0) { LSTM_BODY(=) }     // cell-A waves cover all [2][64][32] slots
    __syncthreads();
    if (ch == 1) { LSTM_BODY(+=) }    // cell-B waves accumulate
    __syncthreads();
#undef LSTM_BODY

    {
        int r = tid >> 2, q = tid & 3;
        if (r < nvalid) {
            int grow = rowList[rowbase + r];
            size_t obase = (size_t)grow * 256 + ob * 32 + q * 8;
            *(float4*)&out[obase]     = *(float4*)&oAcc[r * 32 + q * 8];
            *(float4*)&out[obase + 4] = *(float4*)&oAcc[r * 32 + q * 8 + 4];
            *(float4*)&out[(size_t)NB * 256 + obase]     = *(float4*)&oAcc[2048 + r * 32 + q * 8];
            *(float4*)&out[(size_t)NB * 256 + obase + 4] = *(float4*)&oAcc[2048 + r * 32 + q * 8 + 4];
        }
    }
}

extern "C" void kernel_launch(void* const* d_in, const int* in_sizes, int n_in,
                              void* d_out, int out_size, void* d_ws, size_t ws_size,
                              hipStream_t stream) {
    const float* x  = (const float*)d_in[0];
    const float* c  = (const float*)d_in[1];
    const float* h  = (const float*)d_in[2];
    const float* Wg = (const float*)d_in[3];
    const float* bg = (const float*)d_in[4];
    const float* Wc = (const float*)d_in[5];
    const float* bc = (const float*)d_in[6];
    float* out = (float*)d_out;

    const size_t featsB_bytes = (size_t)NB * DD * 2;        // 16.78 MB
    const size_t w4_bytes     = (size_t)NCOLS * DD * 2;     // 4.19 MB
    const size_t gates_bytes  = (size_t)NB * 4 * 4;         // 0.26 MB
    const size_t counts_bytes = 256;
    const size_t rlist_bytes  = (size_t)6 * 16384 * 4;      // 0.39 MB
    if (ws_size < featsB_bytes + w4_bytes + gates_bytes + counts_bytes + rlist_bytes)
        return;

    char* ws = (char*)d_ws;
    __hip_bfloat16* featsB = (__hip_bfloat16*)ws;
    __hip_bfloat16* W4     = (__hip_bfloat16*)(ws + featsB_bytes);
    float*          gatesW = (float*)(ws + featsB_bytes + w4_bytes);
    int*            counts = (int*)(ws + featsB_bytes + w4_bytes + gates_bytes);
    int*            rowLst = (int*)(ws + featsB_bytes + w4_bytes + gates_bytes + counts_bytes);

    hipMemsetAsync(counts, 0, 32, stream);
    k_pre<<<dim3(5120), dim3(256), 0, stream>>>(x, h, Wc, bc, Wg, featsB, gatesW, W4);
    k_bucket<<<dim3(64), dim3(256), 0, stream>>>(gatesW, counts, rowLst);
    // 2176 = 8 XCD-residues x 34 chunk-groups x 8 obs; blocks with bq>=total exit
    k_main<<<dim3(2176), dim3(256), 0, stream>>>(featsB, W4, c, gatesW, bg,
                                                 counts, rowLst, out);
}

// Round 16
// 103.356 us; speedup vs baseline: 1.2805x; 1.1206x over previous
//
#include <hip/hip_runtime.h>
#include <hip/hip_bf16.h>

// Problem constants
#define NB 16384      // batch rows
#define DD 512        // IN+OUT
#define NCOLS 4096    // 4*OUT*NCELL

typedef __attribute__((ext_vector_type(8))) short short8;
typedef __attribute__((ext_vector_type(4))) float f32x4;

// Fast-approx activations (output tolerance 0.0837 >> 1-ulp rcp/exp2 error):
// v_exp_f32 + v_rcp_f32, ~4-5 VALU instrs vs ~15-20 for libm+fdiv forms.
__device__ __forceinline__ float sigmoidf_(float x) {
    float e = __builtin_amdgcn_exp2f(-1.442695041f * x);   // exp(-x)
    return __builtin_amdgcn_rcpf(1.f + e);                 // saturates cleanly
}
__device__ __forceinline__ float tanhf_(float x) {
    float e = __builtin_amdgcn_exp2f(-2.885390082f * x);   // exp(-2x)
    return 2.f * __builtin_amdgcn_rcpf(1.f + e) - 1.f;     // 2*sigma(2x)-1
}

#define GLOAD_LDS16(g, l) __builtin_amdgcn_global_load_lds( \
    (__attribute__((address_space(1))) void*)(g), \
    (__attribute__((address_space(3))) void*)(l), 16, 0, 0)

// ---------------- P1 (fused): feats->bf16 + ctrl gates | W_gates repack to W4 ----
// W4 layout (R8-proven): chunk c = (((cell*8+ob)*8 + rowg)*16 + kkg)*64 + lane,
// rowg = oh*4 + gate; chunk holds k = kkg*32 + (lane>>4)*8 .. +8 of column
// (cell,gate,ob,oh,oi=lane&15). A wave's B-fragment load in k_main is then
// uniform_base + lane*16 -> one fully-coalesced 1KB wave load.
__global__ void k_pre(const float* __restrict__ x, const float* __restrict__ h,
                      const float* __restrict__ Wc, const float* __restrict__ bc,
                      const float* __restrict__ Wg,
                      __hip_bfloat16* __restrict__ featsB, float* __restrict__ gates,
                      __hip_bfloat16* __restrict__ W4) {
    int bid = blockIdx.x;
    if (bid < 4096) {
        int wave = bid * 4 + (threadIdx.x >> 6);  // == row
        int lane = threadIdx.x & 63;
        int row = wave;
        int k0 = lane * 8;
        const float* src = (k0 < 256) ? (x + (size_t)row * 256 + k0)
                                      : (h + (size_t)row * 256 + k0 - 256);
        float4 f0 = ((const float4*)src)[0];
        float4 f1 = ((const float4*)src)[1];
        float fv[8] = {f0.x, f0.y, f0.z, f0.w, f1.x, f1.y, f1.z, f1.w};
        __hip_bfloat16 tmp[8];
#pragma unroll
        for (int j = 0; j < 8; ++j) tmp[j] = __float2bfloat16(fv[j]);
        *reinterpret_cast<short8*>(featsB + (size_t)row * 512 + k0) =
            *reinterpret_cast<short8*>(tmp);
        float acc[4] = {0.f, 0.f, 0.f, 0.f};
#pragma unroll
        for (int j = 0; j < 8; ++j) {
            float4 w = ((const float4*)Wc)[k0 + j];
            acc[0] += fv[j] * w.x; acc[1] += fv[j] * w.y;
            acc[2] += fv[j] * w.z; acc[3] += fv[j] * w.w;
        }
#pragma unroll
        for (int off = 32; off; off >>= 1) {
#pragma unroll
            for (int c = 0; c < 4; ++c) acc[c] += __shfl_xor(acc[c], off);
        }
        if (lane == 0) {
            float l[4];
#pragma unroll
            for (int c = 0; c < 4; ++c) l[c] = acc[c] + bc[c];
            int i1 = 0;
#pragma unroll
            for (int c = 1; c < 4; ++c) if (l[c] > l[i1]) i1 = c;  // ties -> lowest
            int i2 = -1;
#pragma unroll
            for (int c = 0; c < 4; ++c)
                if (c != i1 && (i2 < 0 || l[c] > l[i2])) i2 = c;
            // selection must match numpy: f32 logits, exact expf here (cheap, once)
            float e = __expf(l[i2] - l[i1]);   // <= 1
            float p1 = 1.f / (1.f + e);
            float p2 = e / (1.f + e);
            float g[4] = {0.f, 0.f, 0.f, 0.f};
            g[i1] = p1; g[i2] = p2;
            float4 gv; gv.x = g[0]; gv.y = g[1]; gv.z = g[2]; gv.w = g[3];
            *(float4*)(gates + (size_t)row * 4) = gv;
        }
    } else {
        int c = (bid - 4096) * 256 + threadIdx.x;   // chunk id, 0..262143
        int lane = c & 63;
        int kkg  = (c >> 6) & 15;
        int rowg = (c >> 10) & 7;
        int ob   = (c >> 13) & 7;
        int cell = c >> 16;
        int oi = lane & 15, hi = lane >> 4;
        int gate = rowg & 3, oh = rowg >> 2;
        int col = cell * 1024 + gate * 256 + ob * 32 + oh * 16 + oi;
        int kb = kkg * 32 + hi * 8;
        __hip_bfloat16 tmp[8];
#pragma unroll
        for (int j = 0; j < 8; ++j)
            tmp[j] = __float2bfloat16(Wg[(size_t)(kb + j) * 4096 + col]);
        *reinterpret_cast<short8*>(W4 + (size_t)c * 8) = *reinterpret_cast<short8*>(tmp);
    }
}

// ---------------- P2: bucket rows by active cell-pair (wave-aggregated atomics) ----
__global__ void k_bucket(const float* __restrict__ gates, int* __restrict__ counts,
                         int* __restrict__ rowList) {
    int row = blockIdx.x * 256 + threadIdx.x;
    int lane = threadIdx.x & 63;
    float4 g = *(const float4*)(gates + (size_t)row * 4);
    int i1 = 0; float m1 = g.x;
    if (g.y > m1) { m1 = g.y; i1 = 1; }
    if (g.z > m1) { m1 = g.z; i1 = 2; }
    if (g.w > m1) { m1 = g.w; i1 = 3; }
    int i2 = -1; float m2 = -1.f;
    if (i1 != 0)             { m2 = g.x; i2 = 0; }
    if (i1 != 1 && g.y > m2) { m2 = g.y; i2 = 1; }
    if (i1 != 2 && g.z > m2) { m2 = g.z; i2 = 2; }
    if (i1 != 3 && g.w > m2) { m2 = g.w; i2 = 3; }
    int a = min(i1, i2), b = max(i1, i2);
    int pid = (a == 0) ? (b - 1) : (a == 1) ? (1 + b) : 5;
#pragma unroll
    for (int q = 0; q < 6; ++q) {
        unsigned long long m = __ballot(pid == q);   // uniform execution
        if (pid == q) {
            int leader = __ffsll((long long)m) - 1;
            int base = 0;
            if (lane == leader) base = atomicAdd(counts + q, __popcll(m));
            base = __shfl(base, leader);
            int prefix = __popcll(m & ((1ull << lane) - 1ull));
            rowList[q * 16384 + base + prefix] = row;
        }
    }
}

// ---------------- Main: pair-bucketed GEMM, B-in-register + A-LDS-dbuf ----------
// K-loop + epilogue structure byte-identical to R14 (epilogue cin/gates
// prefetched to LDS — proven −13 µs). R15 change: fast-approx sigmoid/tanh
// (exp2+rcp) cut epilogue VALU ~1600 -> ~600 instrs/thread.
__launch_bounds__(256, 3)
__global__ void k_main(const __hip_bfloat16* __restrict__ featsB,
                       const __hip_bfloat16* __restrict__ W4,
                       const float* __restrict__ cin,
                       const float* __restrict__ gates,
                       const float* __restrict__ bg,
                       const int* __restrict__ counts,
                       const int* __restrict__ rowList,
                       float* __restrict__ out) {
    __shared__ char smem[25600];          // A[2][8192] | cinS 8K | gatesS 1K
    float* oAcc  = (float*)smem;          // [2][64][32] f32 — aliases A bufs only
    float* cinS  = (float*)(smem + 16384);   // [64][32]
    float* gatesS = (float*)(smem + 24576);  // [64][4]

    int tid = threadIdx.x;
    int wave = tid >> 6, lane = tid & 63;
    int wc = wave;                        // (ch, ohh) selector
    int hi = lane >> 4, lsw = lane & 7, l15 = lane & 15;

    // R10 XCD-clustered decode: lin%8 = XCD = bq%8
    int lin = blockIdx.x;                 // [0, 2176)
    int r_ = lin & 7;
    int v_ = lin >> 3;                    // [0, 272)
    int ob = v_ & 7;
    int bq = r_ + ((v_ >> 3) << 3);       // [0, 272), bq%8 == r_

    int c0_ = counts[0], c1_ = counts[1], c2_ = counts[2],
        c3_ = counts[3], c4_ = counts[4], c5_ = counts[5];
    int s1 = (c0_ + 63) >> 6;
    int s2 = s1 + ((c1_ + 63) >> 6);
    int s3 = s2 + ((c2_ + 63) >> 6);
    int s4 = s3 + ((c3_ + 63) >> 6);
    int s5 = s4 + ((c4_ + 63) >> 6);
    int total = s5 + ((c5_ + 63) >> 6);
    if (bq >= total) return;
    int p, chunk, cnt, cA, cB;
    if      (bq < s1) { p = 0; chunk = bq;      cnt = c0_; cA = 0; cB = 1; }
    else if (bq < s2) { p = 1; chunk = bq - s1; cnt = c1_; cA = 0; cB = 2; }
    else if (bq < s3) { p = 2; chunk = bq - s2; cnt = c2_; cA = 0; cB = 3; }
    else if (bq < s4) { p = 3; chunk = bq - s3; cnt = c3_; cA = 1; cB = 2; }
    else if (bq < s5) { p = 4; chunk = bq - s4; cnt = c4_; cA = 1; cB = 3; }
    else              { p = 5; chunk = bq - s5; cnt = c5_; cA = 2; cB = 3; }
    int nvalid = min(64, cnt - chunk * 64);
    int rowbase = p * 16384 + chunk * 64;

    int ohh = wc & 1;
    int ch  = wc >> 1;
    int cell = ch ? cB : cA;

    // A gather descriptors (R10-proven): 128-B rows = 8 chunks; swizzle key = row&7
    int e0 = tid,        rA0 = e0 >> 3, gA0 = (e0 & 7) ^ (rA0 & 7);
    int e1 = 256 + tid,  rA1 = e1 >> 3, gA1 = (e1 & 7) ^ (rA1 & 7);
    int grA0 = rowList[rowbase + ((rA0 < nvalid) ? rA0 : 0)];
    int grA1 = rowList[rowbase + ((rA1 < nvalid) ? rA1 : 0)];
    const __hip_bfloat16* sA0 = featsB + (size_t)grA0 * 512 + gA0 * 8;
    const __hip_bfloat16* sA1 = featsB + (size_t)grA1 * 512 + gA1 * 8;
    int dA0 = e0 * 16, dA1 = e1 * 16;

    // B wave base in W4 (R8-proven mapping)
    const __hip_bfloat16* bBw =
        W4 + ((size_t)(cell * 8 + ob) * 128 + ohh * 64) * 512 + lane * 8;

    f32x4 acc[4][4];
#pragma unroll
    for (int m = 0; m < 4; ++m)
#pragma unroll
        for (int n = 0; n < 4; ++n)
            acc[m][n] = (f32x4){0.f, 0.f, 0.f, 0.f};

    short8 br[2][4][2];                   // [buf parity][n][kk] — static after unroll

#define STAGE_A(kt_, buf_) do { \
        GLOAD_LDS16(sA0 + (kt_) * 64, smem + (buf_) * 8192 + dA0); \
        GLOAD_LDS16(sA1 + (kt_) * 64, smem + (buf_) * 8192 + dA1); \
    } while (0)
#define LOAD_B(pb_, kt_) do { \
        _Pragma("unroll") \
        for (int n_ = 0; n_ < 4; ++n_) \
            _Pragma("unroll") \
            for (int kk_ = 0; kk_ < 2; ++kk_) \
                br[pb_][n_][kk_] = *reinterpret_cast<const short8*>( \
                    bBw + n_ * 8192 + ((kt_) * 2 + kk_) * 512); \
    } while (0)

    // prologue: tile 0 + EPILOGUE OPERAND PREFETCH (cin/gates -> LDS)
    STAGE_A(0, 0);
    {
        int ec0 = tid,       rc0 = ec0 >> 3, qc0 = ec0 & 7;
        int ec1 = 256 + tid, rc1 = ec1 >> 3, qc1 = ec1 & 7;
        int gr0 = rowList[rowbase + ((rc0 < nvalid) ? rc0 : 0)];
        int gr1 = rowList[rowbase + ((rc1 < nvalid) ? rc1 : 0)];
        GLOAD_LDS16(cin + (size_t)gr0 * 256 + ob * 32 + qc0 * 4,
                    (char*)cinS + ec0 * 16);
        GLOAD_LDS16(cin + (size_t)gr1 * 256 + ob * 32 + qc1 * 4,
                    (char*)cinS + ec1 * 16);
        if (tid < 64) {
            int gr = rowList[rowbase + ((tid < nvalid) ? tid : 0)];
            GLOAD_LDS16(gates + (size_t)gr * 4, (char*)gatesS + tid * 16);
        }
    }
    LOAD_B(0, 0);
    __syncthreads();                      // drains: A(0), cin, gates in LDS

#pragma unroll
    for (int kt = 0; kt < 8; ++kt) {
        const int buf = kt & 1;
        if (kt < 7) {                     // issue next tile's loads BEFORE compute
            STAGE_A(kt + 1, buf ^ 1);
            LOAD_B(buf ^ 1, kt + 1);
        }
        const char* Ab = smem + buf * 8192;
#pragma unroll
        for (int kk = 0; kk < 2; ++kk) {
            short8 fa[4];
#pragma unroll
            for (int m = 0; m < 4; ++m) {
                int row = m * 16 + l15;
                int chunkc = (kk * 4 + hi) ^ lsw;
                fa[m] = *reinterpret_cast<const short8*>(Ab + row * 128 + chunkc * 16);
            }
#pragma unroll
            for (int m = 0; m < 4; ++m)
#pragma unroll
                for (int n = 0; n < 4; ++n)
                    acc[m][n] = __builtin_amdgcn_mfma_f32_16x16x32_bf16(
                        fa[m], br[buf][n][kk], acc[m][n], 0, 0, 0);
        }
        __syncthreads();  // reads of buf done; vmcnt(0) drain covered by compute
    }
#undef STAGE_A
#undef LOAD_B

    // ---- epilogue: all operands in LDS/registers; fast-approx activations ----
    int og = ob * 32 + ohh * 16 + l15;    // global o in [0,256)
    float bb0 = bg[cell * 1024 + 0 * 256 + og];
    float bb1 = bg[cell * 1024 + 1 * 256 + og];
    float bb2 = bg[cell * 1024 + 2 * 256 + og];
    float bb3 = bg[cell * 1024 + 3 * 256 + og];

#define LSTM_BODY(STORE_OP) \
    _Pragma("unroll") \
    for (int m = 0; m < 4; ++m) { \
        _Pragma("unroll") \
        for (int reg = 0; reg < 4; ++reg) { \
            int r = m * 16 + hi * 4 + reg; \
            float gw = gatesS[r * 4 + cell]; \
            float iv = sigmoidf_(acc[m][0][reg] + bb0); \
            float jv = acc[m][1][reg] + bb1; \
            float fv = sigmoidf_(acc[m][2][reg] + bb2); \
            float ov = sigmoidf_(acc[m][3][reg] + bb3); \
            float cv = cinS[r * 32 + ohh * 16 + l15]; \
            float ncl = fv * cv + iv * tanhf_(jv); \
            float nhl = ov * tanhf_(ncl); \
            oAcc[r * 32 + ohh * 16 + l15] STORE_OP gw * nhl; \
            oAcc[2048 + r * 32 + ohh * 16 + l15] STORE_OP gw * ncl; \
        } \
    }

    if (ch == 0) { LSTM_BODY(=) }     // cell-A waves cover all [2][64][32] slots
    __syncthreads();
    if (ch == 1) { LSTM_BODY(+=) }    // cell-B waves accumulate
    __syncthreads();
#undef LSTM_BODY

    {
        int r = tid >> 2, q = tid & 3;
        if (r < nvalid) {
            int grow = rowList[rowbase + r];
            size_t obase = (size_t)grow * 256 + ob * 32 + q * 8;
            *(float4*)&out[obase]     = *(float4*)&oAcc[r * 32 + q * 8];
            *(float4*)&out[obase + 4] = *(float4*)&oAcc[r * 32 + q * 8 + 4];
            *(float4*)&out[(size_t)NB * 256 + obase]     = *(float4*)&oAcc[2048 + r * 32 + q * 8];
            *(float4*)&out[(size_t)NB * 256 + obase + 4] = *(float4*)&oAcc[2048 + r * 32 + q * 8 + 4];
        }
    }
}

extern "C" void kernel_launch(void* const* d_in, const int* in_sizes, int n_in,
                              void* d_out, int out_size, void* d_ws, size_t ws_size,
                              hipStream_t stream) {
    const float* x  = (const float*)d_in[0];
    const float* c  = (const float*)d_in[1];
    const float* h  = (const float*)d_in[2];
    const float* Wg = (const float*)d_in[3];
    const float* bg = (const float*)d_in[4];
    const float* Wc = (const float*)d_in[5];
    const float* bc = (const float*)d_in[6];
    float* out = (float*)d_out;

    const size_t featsB_bytes = (size_t)NB * DD * 2;        // 16.78 MB
    const size_t w4_bytes     = (size_t)NCOLS * DD * 2;     // 4.19 MB
    const size_t gates_bytes  = (size_t)NB * 4 * 4;         // 0.26 MB
    const size_t counts_bytes = 256;
    const size_t rlist_bytes  = (size_t)6 * 16384 * 4;      // 0.39 MB
    if (ws_size < featsB_bytes + w4_bytes + gates_bytes + counts_bytes + rlist_bytes)
        return;

    char* ws = (char*)d_ws;
    __hip_bfloat16* featsB = (__hip_bfloat16*)ws;
    __hip_bfloat16* W4     = (__hip_bfloat16*)(ws + featsB_bytes);
    float*          gatesW = (float*)(ws + featsB_bytes + w4_bytes);
    int*            counts = (int*)(ws + featsB_bytes + w4_bytes + gates_bytes);
    int*            rowLst = (int*)(ws + featsB_bytes + w4_bytes + gates_bytes + counts_bytes);

    hipMemsetAsync(counts, 0, 32, stream);
    k_pre<<<dim3(5120), dim3(256), 0, stream>>>(x, h, Wc, bc, Wg, featsB, gatesW, W4);
    k_bucket<<<dim3(64), dim3(256), 0, stream>>>(gatesW, counts, rowLst);
    // 2176 = 8 XCD-residues x 34 chunk-groups x 8 obs; blocks with bq>=total exit
    k_main<<<dim3(2176), dim3(256), 0, stream>>>(featsB, W4, c, gatesW, bg,
                                                 counts, rowLst, out);
}